// Round 3
// 360.143 us; speedup vs baseline: 1.0673x; 1.0673x over previous
//
#include <hip/hip_runtime.h>
#include <hip/hip_bf16.h>

// GCN encoder: 2x GCNConv, symmetric norm, relu + L2 rownorm between.
// Pull aggregation over CSR-by-dst, bf16 intermediates (f32 accumulate).
// R7: CSR built with ZERO global atomics (LDS histograms + scans).
// R8 (2nd resubmit; rounds 1-2 died on container acquisition, kernel never
// ran -- source audited OOB/hang-clean): (a) agg inner loops fully batched:
// the serial remainder loop (avg ~3.5 chained-latency iterations per node at
// Poisson(16) degree) is replaced by one masked 8-wide batch; (b) dinv[src]
// folded into the GEMM epilogue (xw' = (x@W)*dinv[row]), so the per-edge
// dinv gather and multiply disappear: agg_i = dinv_i*(xw'_i + sum xw'_src).
// Identical math, same single bf16 rounding point.

#define IN_CH 128
#define HID 128
#define OUT_CH 64
#define NBLK 128          // chunk blocks for hist/scatter
#define MAXNB 1568        // >= ceil(100000/64)=1563 buckets

typedef unsigned int uint_t;
typedef unsigned short ushort_t;

__device__ __forceinline__ ushort_t f32_to_bf16_rn(float f) {
    uint_t u = __float_as_uint(f);
    u = (u + 0x7fffu + ((u >> 16) & 1u)) >> 16;
    return (ushort_t)u;
}
__device__ __forceinline__ float bf16lo_to_f32(uint_t u) { return __uint_as_float(u << 16); }
__device__ __forceinline__ float bf16hi_to_f32(uint_t u) { return __uint_as_float(u & 0xffff0000u); }

// ---------------- phase 1: per-block LDS bucket histogram ----------------
__global__ __launch_bounds__(256) void hist_kernel(const int* __restrict__ dst, int E,
                                                   int chunk, int NB,
                                                   int* __restrict__ blk_cnt) {
    __shared__ int hist[MAXNB];
    int tid = threadIdx.x;
    int blk = blockIdx.x;
    for (int b = tid; b < NB; b += 256) hist[b] = 0;
    __syncthreads();
    int start = blk * chunk;
    int end = start + chunk; if (end > E) end = E;
    int e = start + tid;
    for (; e + 768 < end; e += 1024) {
        int d0 = dst[e], d1 = dst[e + 256], d2 = dst[e + 512], d3 = dst[e + 768];
        atomicAdd(&hist[d0 >> 6], 1);
        atomicAdd(&hist[d1 >> 6], 1);
        atomicAdd(&hist[d2 >> 6], 1);
        atomicAdd(&hist[d3 >> 6], 1);
    }
    for (; e < end; e += 256) atomicAdd(&hist[dst[e] >> 6], 1);
    __syncthreads();
    for (int b = tid; b < NB; b += 256) blk_cnt[blk * NB + b] = hist[b];
}

// ---------------- phase 2a: bucket totals (column sums) ----------------
__global__ __launch_bounds__(256) void btot_kernel(const int* __restrict__ blk_cnt,
                                                   int NB, int* __restrict__ btot) {
    int b = blockIdx.x * 256 + threadIdx.x;
    if (b < NB) {
        int sum = 0;
        #pragma unroll 8
        for (int blk = 0; blk < NBLK; blk++) sum += blk_cnt[blk * NB + b];
        btot[b] = sum;
    }
}

// ---------------- phase 2b: single-block exclusive scan over buckets --------------
__global__ __launch_bounds__(256) void scan_kernel(const int* __restrict__ btot, int NB,
                                                   int* __restrict__ bucket_base,
                                                   int* __restrict__ row_start,
                                                   int n, int E) {
    __shared__ int sdata[256];
    __shared__ int carryS;
    int tid = threadIdx.x;
    if (tid == 0) carryS = 0;
    __syncthreads();
    int nchunks = (NB + 255) / 256;
    for (int c = 0; c < nchunks; c++) {
        int i = c * 256 + tid;
        int v = (i < NB) ? btot[i] : 0;
        sdata[tid] = v;
        __syncthreads();
        for (int off = 1; off < 256; off <<= 1) {
            int t = (tid >= off) ? sdata[tid - off] : 0;
            __syncthreads();
            sdata[tid] += t;
            __syncthreads();
        }
        if (i < NB) bucket_base[i] = carryS + sdata[tid] - v;
        __syncthreads();
        if (tid == 0) carryS += sdata[255];
        __syncthreads();
    }
    if (tid == 0) {
        bucket_base[NB] = E;
        row_start[n] = E;
    }
}

// ---------------- phase 2c: per-bucket exclusive scan over blocks -----------------
__global__ __launch_bounds__(256) void colscan_kernel(const int* __restrict__ blk_cnt,
                                                      const int* __restrict__ bucket_base,
                                                      int NB, int* __restrict__ blk_start) {
    __shared__ int tile[NBLK][16];
    int tid = threadIdx.x;
    int b0 = blockIdx.x * 16;
    for (int idx = tid; idx < NBLK * 16; idx += 256) {
        int blk = idx >> 4, b = idx & 15;
        if (b0 + b < NB) tile[blk][b] = blk_cnt[blk * NB + b0 + b];
    }
    __syncthreads();
    if (tid < 16 && b0 + tid < NB) {
        int running = bucket_base[b0 + tid];
        for (int blk = 0; blk < NBLK; blk++) {
            int t = tile[blk][tid];
            tile[blk][tid] = running;
            running += t;
        }
    }
    __syncthreads();
    for (int idx = tid; idx < NBLK * 16; idx += 256) {
        int blk = idx >> 4, b = idx & 15;
        if (b0 + b < NB) blk_start[blk * NB + b0 + b] = tile[blk][b];
    }
}

// ---------------- phase 3: scatter, LDS tickets only ----------------
// pack: src (26 bits) | (dst & 63) << 26.
__global__ __launch_bounds__(256) void scatter_kernel(const int* __restrict__ src,
                                                      const int* __restrict__ dst,
                                                      int E, int chunk, int NB,
                                                      const int* __restrict__ blk_start,
                                                      uint_t* __restrict__ pairs) {
    __shared__ int cur[MAXNB];
    int tid = threadIdx.x;
    int blk = blockIdx.x;
    for (int b = tid; b < NB; b += 256) cur[b] = blk_start[blk * NB + b];
    __syncthreads();
    int start = blk * chunk;
    int end = start + chunk; if (end > E) end = E;
    int e = start + tid;
    for (; e + 768 < end; e += 1024) {
        int d0 = dst[e], d1 = dst[e + 256], d2 = dst[e + 512], d3 = dst[e + 768];
        int s0 = src[e], s1 = src[e + 256], s2 = src[e + 512], s3 = src[e + 768];
        int p0 = atomicAdd(&cur[d0 >> 6], 1);
        int p1 = atomicAdd(&cur[d1 >> 6], 1);
        int p2 = atomicAdd(&cur[d2 >> 6], 1);
        int p3 = atomicAdd(&cur[d3 >> 6], 1);
        pairs[p0] = (uint_t)s0 | ((uint_t)(d0 & 63) << 26);
        pairs[p1] = (uint_t)s1 | ((uint_t)(d1 & 63) << 26);
        pairs[p2] = (uint_t)s2 | ((uint_t)(d2 & 63) << 26);
        pairs[p3] = (uint_t)s3 | ((uint_t)(d3 & 63) << 26);
    }
    for (; e < end; e += 256) {
        int d = dst[e], s = src[e];
        int p = atomicAdd(&cur[d >> 6], 1);
        pairs[p] = (uint_t)s | ((uint_t)(d & 63) << 26);
    }
}

// ---------------- phase 4: fine fill -- per bucket: counts, row_start, dinv, csr ---
__global__ __launch_bounds__(256) void fine_fill_kernel(const uint_t* __restrict__ pairs,
                                                        const int* __restrict__ bucket_base,
                                                        int* __restrict__ row_start,
                                                        float* __restrict__ dinv,
                                                        int* __restrict__ csr_src,
                                                        int n) {
    __shared__ int cnt64[64];
    __shared__ int cur[64];
    int b = blockIdx.x;
    int node0 = b << 6;
    int tid = threadIdx.x;
    if (tid < 64) cnt64[tid] = 0;
    __syncthreads();
    int start = bucket_base[b];
    int end = bucket_base[b + 1];
    int e = start + tid;
    for (; e + 768 < end; e += 1024) {
        uint_t u0 = pairs[e], u1 = pairs[e + 256], u2 = pairs[e + 512], u3 = pairs[e + 768];
        atomicAdd(&cnt64[u0 >> 26], 1);
        atomicAdd(&cnt64[u1 >> 26], 1);
        atomicAdd(&cnt64[u2 >> 26], 1);
        atomicAdd(&cnt64[u3 >> 26], 1);
    }
    for (; e < end; e += 256) atomicAdd(&cnt64[pairs[e] >> 26], 1);
    __syncthreads();
    if (tid < 64) {
        int c = cnt64[tid];
        int v = c;
        #pragma unroll
        for (int off = 1; off < 64; off <<= 1) {
            int u = __shfl_up(v, off, 64);
            if (tid >= off) v += u;
        }
        int excl = start + v - c;
        if (node0 + tid < n) {
            row_start[node0 + tid] = excl;
            dinv[node0 + tid] = rsqrtf((float)(c + 1));  // +1 self loop
        }
        cur[tid] = excl;
    }
    __syncthreads();
    e = start + tid;
    for (; e + 768 < end; e += 1024) {
        uint_t u0 = pairs[e], u1 = pairs[e + 256], u2 = pairs[e + 512], u3 = pairs[e + 768];
        int p0 = atomicAdd(&cur[u0 >> 26], 1);
        int p1 = atomicAdd(&cur[u1 >> 26], 1);
        int p2 = atomicAdd(&cur[u2 >> 26], 1);
        int p3 = atomicAdd(&cur[u3 >> 26], 1);
        csr_src[p0] = (int)(u0 & 0x3FFFFFFu);
        csr_src[p1] = (int)(u1 & 0x3FFFFFFu);
        csr_src[p2] = (int)(u2 & 0x3FFFFFFu);
        csr_src[p3] = (int)(u3 & 0x3FFFFFFu);
    }
    for (; e < end; e += 256) {
        uint_t u = pairs[e];
        int p = atomicAdd(&cur[u >> 26], 1);
        csr_src[p] = (int)(u & 0x3FFFFFFu);
    }
}

// ---------------- GEMM: Y[n x NCOL] = (X[n x 128] * W[128 x NCOL]) * rowscale[row] --
template <int NCOL, bool BF16_IN>
__global__ __launch_bounds__(256, 3) void gemm_kernel(const void* __restrict__ Xv,
                                                      const float* __restrict__ W,
                                                      const float* __restrict__ rowscale,
                                                      ushort_t* __restrict__ Y, int nrows) {
    constexpr int K = 128;
    constexpr int KT = 32;
    constexpr int CPL = NCOL / 64;       // cols per lane (2 or 1)
    __shared__ __align__(16) float Xs[64 * K];      // 32 KB
    __shared__ __align__(16) float Ws[KT * NCOL];   // 16 KB / 8 KB

    int tid = threadIdx.x;
    int wave = tid >> 6;
    int lane = tid & 63;
    int rowBase = blockIdx.x * 64;
    int r0 = wave * 16;

    if (BF16_IN) {
        const uint_t* X = (const uint_t*)Xv;
        for (int j = tid; j < 64 * (K / 2); j += 256) {
            int r = j >> 6;
            int c = j & 63;
            int gr = rowBase + r;
            uint_t u = (gr < nrows) ? X[(size_t)gr * (K / 2) + c] : 0u;
            Xs[r * K + 2 * c]     = bf16lo_to_f32(u);
            Xs[r * K + 2 * c + 1] = bf16hi_to_f32(u);
        }
    } else {
        const float4* X4 = (const float4*)Xv;
        float4* Xs4 = (float4*)Xs;
        for (int j = tid; j < 64 * (K / 4); j += 256) {
            int r = j >> 5;
            int gr = rowBase + r;
            float4 v = make_float4(0.f, 0.f, 0.f, 0.f);
            if (gr < nrows) v = X4[(size_t)gr * (K / 4) + (j & 31)];
            Xs4[j] = v;
        }
    }

    float acc[16][CPL];
    #pragma unroll
    for (int r = 0; r < 16; r++)
        #pragma unroll
        for (int c = 0; c < CPL; c++) acc[r][c] = 0.f;

    #pragma unroll 1
    for (int kt = 0; kt < K; kt += KT) {
        __syncthreads();
        {
            float4* Ws4 = (float4*)Ws;
            const float4* W4 = (const float4*)W;
            for (int j = tid; j < KT * (NCOL / 4); j += 256)
                Ws4[j] = W4[(size_t)kt * (NCOL / 4) + j];
        }
        __syncthreads();
        #pragma unroll 2
        for (int k4 = 0; k4 < KT; k4 += 4) {
            float wv[4][CPL];
            #pragma unroll
            for (int kk = 0; kk < 4; kk++)
                #pragma unroll
                for (int c = 0; c < CPL; c++)
                    wv[kk][c] = Ws[(k4 + kk) * NCOL + lane * CPL + c];
            #pragma unroll
            for (int r = 0; r < 16; r++) {
                float4 xv = *(const float4*)&Xs[(r0 + r) * K + kt + k4];  // broadcast
                #pragma unroll
                for (int c = 0; c < CPL; c++) {
                    acc[r][c] = fmaf(xv.x, wv[0][c], acc[r][c]);
                    acc[r][c] = fmaf(xv.y, wv[1][c], acc[r][c]);
                    acc[r][c] = fmaf(xv.z, wv[2][c], acc[r][c]);
                    acc[r][c] = fmaf(xv.w, wv[3][c], acc[r][c]);
                }
            }
        }
    }

    #pragma unroll
    for (int r = 0; r < 16; r++) {
        int gr = rowBase + r0 + r;
        if (gr < nrows) {
            float rs = rowscale[gr];
            if (CPL == 2) {
                uint_t u = (uint_t)f32_to_bf16_rn(acc[r][0] * rs) |
                           ((uint_t)f32_to_bf16_rn(acc[r][CPL - 1] * rs) << 16);
                ((uint_t*)(Y + (size_t)gr * NCOL))[lane] = u;
            } else {
                Y[(size_t)gr * NCOL + lane] = f32_to_bf16_rn(acc[r][0] * rs);
            }
        }
    }
}

// ---------------- aggregation layer 1: pull + bias + relu + L2 rownorm ----------------
// xw rows are pre-scaled by dinv[src]; result = dinv[i]*(self + sum) + b1.
__global__ __launch_bounds__(256) void agg1_kernel(const ushort_t* __restrict__ xw,
                                                   const int* __restrict__ csr_src,
                                                   const int* __restrict__ row_start,
                                                   const float* __restrict__ dinv,
                                                   const float* __restrict__ b1,
                                                   ushort_t* __restrict__ h, int n) {
    int wid = (blockIdx.x * 256 + threadIdx.x) >> 6;
    int lane = threadIdx.x & 63;
    if (wid >= n) return;
    int i = wid;
    float di = dinv[i];
    int e0 = row_start[i], e1 = row_start[i + 1];
    uint_t su = ((const uint_t*)(xw + (size_t)i * HID))[lane];
    float ax = bf16lo_to_f32(su), ay = bf16hi_to_f32(su);
    int e = e0;
    // full 8-batches: pure adds (dinv[src] pre-folded into xw rows)
    for (; e + 8 <= e1; e += 8) {
        int s[8];
        #pragma unroll
        for (int j = 0; j < 8; j++) s[j] = csr_src[e + j];
        uint_t v[8];
        #pragma unroll
        for (int j = 0; j < 8; j++)
            v[j] = ((const uint_t*)(xw + (size_t)s[j] * HID))[lane];
        #pragma unroll
        for (int j = 0; j < 8; j++) {
            ax += bf16lo_to_f32(v[j]);
            ay += bf16hi_to_f32(v[j]);
        }
    }
    // masked tail batch replaces the old serial remainder loop.
    // Padded slots re-load the last row (L1-hot) with coefficient 0.
    if (e < e1) {
        int last = e1 - 1;
        int s[8];
        #pragma unroll
        for (int j = 0; j < 8; j++) {
            int idx = e + j;
            s[j] = csr_src[idx <= last ? idx : last];
        }
        uint_t v[8];
        #pragma unroll
        for (int j = 0; j < 8; j++)
            v[j] = ((const uint_t*)(xw + (size_t)s[j] * HID))[lane];
        #pragma unroll
        for (int j = 0; j < 8; j++) {
            float c = (e + j <= last) ? 1.0f : 0.0f;
            ax = fmaf(bf16lo_to_f32(v[j]), c, ax);
            ay = fmaf(bf16hi_to_f32(v[j]), c, ay);
        }
    }
    ax = fmaf(ax, di, b1[lane * 2]);
    ay = fmaf(ay, di, b1[lane * 2 + 1]);
    ax = fmaxf(ax, 0.f);
    ay = fmaxf(ay, 0.f);
    float ss = ax * ax + ay * ay;
    #pragma unroll
    for (int m = 32; m >= 1; m >>= 1) ss += __shfl_xor(ss, m, 64);
    float scale = 1.0f / fmaxf(sqrtf(ss), 1e-12f);
    uint_t u = (uint_t)f32_to_bf16_rn(ax * scale) |
               ((uint_t)f32_to_bf16_rn(ay * scale) << 16);
    ((uint_t*)(h + (size_t)i * HID))[lane] = u;
}

// ---------------- aggregation layer 2: pull + bias -> d_out (f32) ----------------
// hw rows pre-scaled by dinv[src]; result = dinv[i]*(self + sum) + b2.
__global__ __launch_bounds__(256) void agg2_kernel(const ushort_t* __restrict__ hw,
                                                   const int* __restrict__ csr_src,
                                                   const int* __restrict__ row_start,
                                                   const float* __restrict__ dinv,
                                                   const float* __restrict__ b2,
                                                   float* __restrict__ out, int n) {
    int wid = (blockIdx.x * 256 + threadIdx.x) >> 6;
    int lane = threadIdx.x & 63;
    int i = wid * 2 + (lane >> 5);
    int l = lane & 31;
    if (i >= n) return;
    float di = dinv[i];
    uint_t su = ((const uint_t*)(hw + (size_t)i * OUT_CH))[l];
    float ax = bf16lo_to_f32(su), ay = bf16hi_to_f32(su);
    int e0 = row_start[i], e1 = row_start[i + 1];
    int e = e0;
    for (; e + 8 <= e1; e += 8) {
        int s[8];
        #pragma unroll
        for (int j = 0; j < 8; j++) s[j] = csr_src[e + j];
        uint_t v[8];
        #pragma unroll
        for (int j = 0; j < 8; j++)
            v[j] = ((const uint_t*)(hw + (size_t)s[j] * OUT_CH))[l];
        #pragma unroll
        for (int j = 0; j < 8; j++) {
            ax += bf16lo_to_f32(v[j]);
            ay += bf16hi_to_f32(v[j]);
        }
    }
    if (e < e1) {
        int last = e1 - 1;
        int s[8];
        #pragma unroll
        for (int j = 0; j < 8; j++) {
            int idx = e + j;
            s[j] = csr_src[idx <= last ? idx : last];
        }
        uint_t v[8];
        #pragma unroll
        for (int j = 0; j < 8; j++)
            v[j] = ((const uint_t*)(hw + (size_t)s[j] * OUT_CH))[l];
        #pragma unroll
        for (int j = 0; j < 8; j++) {
            float c = (e + j <= last) ? 1.0f : 0.0f;
            ax = fmaf(bf16lo_to_f32(v[j]), c, ax);
            ay = fmaf(bf16hi_to_f32(v[j]), c, ay);
        }
    }
    ax = fmaf(ax, di, b2[l * 2]);
    ay = fmaf(ay, di, b2[l * 2 + 1]);
    ((float2*)(out + (size_t)i * OUT_CH))[l] = make_float2(ax, ay);
}

extern "C" void kernel_launch(void* const* d_in, const int* in_sizes, int n_in,
                              void* d_out, int out_size, void* d_ws, size_t ws_size,
                              hipStream_t stream) {
    const float* x  = (const float*)d_in[0];
    const int*   ei = (const int*)d_in[1];
    const float* W1 = (const float*)d_in[2];
    const float* b1 = (const float*)d_in[3];
    const float* W2 = (const float*)d_in[4];
    const float* b2 = (const float*)d_in[5];
    float* out = (float*)d_out;

    const int N = in_sizes[0] / IN_CH;     // 100000
    const int E = in_sizes[1] / 2;         // 1600000
    const int* src = ei;
    const int* dst = ei + E;
    const int NB = (N + 63) / 64;          // buckets (1563)
    const int chunk = (E + NBLK - 1) / NBLK;

    // ---- workspace carve ----
    char* base = (char*)d_ws;
    size_t off = 0;
    auto alloc = [&](size_t bytes) -> void* {
        void* p = base + off;
        off = (off + bytes + 255) & ~(size_t)255;
        return p;
    };
    int*      blk_cnt     = (int*)alloc((size_t)NBLK * NB * 4);
    int*      blk_start   = (int*)alloc((size_t)NBLK * NB * 4);
    int*      btot        = (int*)alloc((size_t)NB * 4);
    int*      bucket_base = (int*)alloc((size_t)(NB + 1) * 4);
    int*      row_start   = (int*)alloc((size_t)(N + 1) * 4);
    float*    dinv        = (float*)alloc((size_t)N * 4);
    int*      csr_src     = (int*)alloc((size_t)E * 4);
    uint_t*   pairs       = (uint_t*)alloc((size_t)E * 4);
    ushort_t* xw          = (ushort_t*)alloc((size_t)N * HID * 2);
    ushort_t* h           = (ushort_t*)alloc((size_t)N * HID * 2);
    ushort_t* hw          = (ushort_t*)alloc((size_t)N * OUT_CH * 2);
    (void)ws_size;

    // CSR build -- no global atomics anywhere
    hist_kernel<<<NBLK, 256, 0, stream>>>(dst, E, chunk, NB, blk_cnt);
    btot_kernel<<<(NB + 255) / 256, 256, 0, stream>>>(blk_cnt, NB, btot);
    scan_kernel<<<1, 256, 0, stream>>>(btot, NB, bucket_base, row_start, N, E);
    colscan_kernel<<<(NB + 15) / 16, 256, 0, stream>>>(blk_cnt, bucket_base, NB, blk_start);
    scatter_kernel<<<NBLK, 256, 0, stream>>>(src, dst, E, chunk, NB, blk_start, pairs);
    fine_fill_kernel<<<NB, 256, 0, stream>>>(pairs, bucket_base, row_start, dinv,
                                             csr_src, N);

    // layer 1 (xw pre-scaled by dinv[row])
    gemm_kernel<128, false><<<(N + 63) / 64, 256, 0, stream>>>(x, W1, dinv, xw, N);
    agg1_kernel<<<(N * 64 + 255) / 256, 256, 0, stream>>>(xw, csr_src, row_start,
                                                          dinv, b1, h, N);
    // layer 2 (hw pre-scaled by dinv[row])
    gemm_kernel<64, true><<<(N + 63) / 64, 256, 0, stream>>>(h, W2, dinv, hw, N);
    int waves2 = (N + 1) / 2;
    agg2_kernel<<<(waves2 * 64 + 255) / 256, 256, 0, stream>>>(hw, csr_src, row_start,
                                                               dinv, b2, out, N);
}

// Round 4
// 346.827 us; speedup vs baseline: 1.1083x; 1.0384x over previous
//
#include <hip/hip_runtime.h>
#include <hip/hip_bf16.h>

// GCN encoder: 2x GCNConv, symmetric norm, relu + L2 rownorm between.
// Pull aggregation over CSR-by-dst, bf16 intermediates (f32 accumulate).
// R7: CSR built with ZERO global atomics (LDS histograms + scans).
// R8: agg loops fully batched (masked 8-wide tail); dinv[src] folded into
//     GEMM epilogue. 384 -> 360 us; layer-1 f32 vector GEMM now dominates
//     (75 us, MfmaUtil=0, 45 TF on the 157 TF vector pipe).
// R9 (this round): both GEMMs moved to MFMA 16x16x32 bf16 with hi/lo split
// (x ~ x_hi + x_lo, bf16 each): x*w ~ xh*wh + xh*wl + xl*wh, error ~2^-17
// => f32-equivalent accuracy, matrix pipe instead of vector pipe.
// Layer-2's A (h) is already bf16 => exact, 2 terms only. LDS-free design:
// A fragments loaded straight to registers (coalesced 128B row segments),
// B fragments are contiguous 16B loads from pre-transposed bf16 hi/lo W
// (prep kernel), L1/L2-resident. D mapping: col=lane&15, row=(lane>>4)*4+reg.

#define IN_CH 128
#define HID 128
#define OUT_CH 64
#define NBLK 128          // chunk blocks for hist/scatter
#define MAXNB 1568        // >= ceil(100000/64)=1563 buckets

typedef unsigned int uint_t;
typedef unsigned short ushort_t;
typedef __attribute__((ext_vector_type(8))) short bf16x8;
typedef __attribute__((ext_vector_type(4))) float f32x4;

__device__ __forceinline__ ushort_t f32_to_bf16_rn(float f) {
    uint_t u = __float_as_uint(f);
    u = (u + 0x7fffu + ((u >> 16) & 1u)) >> 16;
    return (ushort_t)u;
}
__device__ __forceinline__ float bf16lo_to_f32(uint_t u) { return __uint_as_float(u << 16); }
__device__ __forceinline__ float bf16hi_to_f32(uint_t u) { return __uint_as_float(u & 0xffff0000u); }

// ---------------- phase 1: per-block LDS bucket histogram ----------------
__global__ __launch_bounds__(256) void hist_kernel(const int* __restrict__ dst, int E,
                                                   int chunk, int NB,
                                                   int* __restrict__ blk_cnt) {
    __shared__ int hist[MAXNB];
    int tid = threadIdx.x;
    int blk = blockIdx.x;
    for (int b = tid; b < NB; b += 256) hist[b] = 0;
    __syncthreads();
    int start = blk * chunk;
    int end = start + chunk; if (end > E) end = E;
    int e = start + tid;
    for (; e + 768 < end; e += 1024) {
        int d0 = dst[e], d1 = dst[e + 256], d2 = dst[e + 512], d3 = dst[e + 768];
        atomicAdd(&hist[d0 >> 6], 1);
        atomicAdd(&hist[d1 >> 6], 1);
        atomicAdd(&hist[d2 >> 6], 1);
        atomicAdd(&hist[d3 >> 6], 1);
    }
    for (; e < end; e += 256) atomicAdd(&hist[dst[e] >> 6], 1);
    __syncthreads();
    for (int b = tid; b < NB; b += 256) blk_cnt[blk * NB + b] = hist[b];
}

// ---------------- phase 2a: bucket totals (column sums) ----------------
__global__ __launch_bounds__(256) void btot_kernel(const int* __restrict__ blk_cnt,
                                                   int NB, int* __restrict__ btot) {
    int b = blockIdx.x * 256 + threadIdx.x;
    if (b < NB) {
        int sum = 0;
        #pragma unroll 8
        for (int blk = 0; blk < NBLK; blk++) sum += blk_cnt[blk * NB + b];
        btot[b] = sum;
    }
}

// ---------------- phase 2b: single-block exclusive scan over buckets --------------
__global__ __launch_bounds__(256) void scan_kernel(const int* __restrict__ btot, int NB,
                                                   int* __restrict__ bucket_base,
                                                   int* __restrict__ row_start,
                                                   int n, int E) {
    __shared__ int sdata[256];
    __shared__ int carryS;
    int tid = threadIdx.x;
    if (tid == 0) carryS = 0;
    __syncthreads();
    int nchunks = (NB + 255) / 256;
    for (int c = 0; c < nchunks; c++) {
        int i = c * 256 + tid;
        int v = (i < NB) ? btot[i] : 0;
        sdata[tid] = v;
        __syncthreads();
        for (int off = 1; off < 256; off <<= 1) {
            int t = (tid >= off) ? sdata[tid - off] : 0;
            __syncthreads();
            sdata[tid] += t;
            __syncthreads();
        }
        if (i < NB) bucket_base[i] = carryS + sdata[tid] - v;
        __syncthreads();
        if (tid == 0) carryS += sdata[255];
        __syncthreads();
    }
    if (tid == 0) {
        bucket_base[NB] = E;
        row_start[n] = E;
    }
}

// ---------------- phase 2c: per-bucket exclusive scan over blocks -----------------
__global__ __launch_bounds__(256) void colscan_kernel(const int* __restrict__ blk_cnt,
                                                      const int* __restrict__ bucket_base,
                                                      int NB, int* __restrict__ blk_start) {
    __shared__ int tile[NBLK][16];
    int tid = threadIdx.x;
    int b0 = blockIdx.x * 16;
    for (int idx = tid; idx < NBLK * 16; idx += 256) {
        int blk = idx >> 4, b = idx & 15;
        if (b0 + b < NB) tile[blk][b] = blk_cnt[blk * NB + b0 + b];
    }
    __syncthreads();
    if (tid < 16 && b0 + tid < NB) {
        int running = bucket_base[b0 + tid];
        for (int blk = 0; blk < NBLK; blk++) {
            int t = tile[blk][tid];
            tile[blk][tid] = running;
            running += t;
        }
    }
    __syncthreads();
    for (int idx = tid; idx < NBLK * 16; idx += 256) {
        int blk = idx >> 4, b = idx & 15;
        if (b0 + b < NB) blk_start[blk * NB + b0 + b] = tile[blk][b];
    }
}

// ---------------- phase 3: scatter, LDS tickets only ----------------
// pack: src (26 bits) | (dst & 63) << 26.
__global__ __launch_bounds__(256) void scatter_kernel(const int* __restrict__ src,
                                                      const int* __restrict__ dst,
                                                      int E, int chunk, int NB,
                                                      const int* __restrict__ blk_start,
                                                      uint_t* __restrict__ pairs) {
    __shared__ int cur[MAXNB];
    int tid = threadIdx.x;
    int blk = blockIdx.x;
    for (int b = tid; b < NB; b += 256) cur[b] = blk_start[blk * NB + b];
    __syncthreads();
    int start = blk * chunk;
    int end = start + chunk; if (end > E) end = E;
    int e = start + tid;
    for (; e + 768 < end; e += 1024) {
        int d0 = dst[e], d1 = dst[e + 256], d2 = dst[e + 512], d3 = dst[e + 768];
        int s0 = src[e], s1 = src[e + 256], s2 = src[e + 512], s3 = src[e + 768];
        int p0 = atomicAdd(&cur[d0 >> 6], 1);
        int p1 = atomicAdd(&cur[d1 >> 6], 1);
        int p2 = atomicAdd(&cur[d2 >> 6], 1);
        int p3 = atomicAdd(&cur[d3 >> 6], 1);
        pairs[p0] = (uint_t)s0 | ((uint_t)(d0 & 63) << 26);
        pairs[p1] = (uint_t)s1 | ((uint_t)(d1 & 63) << 26);
        pairs[p2] = (uint_t)s2 | ((uint_t)(d2 & 63) << 26);
        pairs[p3] = (uint_t)s3 | ((uint_t)(d3 & 63) << 26);
    }
    for (; e < end; e += 256) {
        int d = dst[e], s = src[e];
        int p = atomicAdd(&cur[d >> 6], 1);
        pairs[p] = (uint_t)s | ((uint_t)(d & 63) << 26);
    }
}

// ---------------- phase 4: fine fill -- per bucket: counts, row_start, dinv, csr ---
__global__ __launch_bounds__(256) void fine_fill_kernel(const uint_t* __restrict__ pairs,
                                                        const int* __restrict__ bucket_base,
                                                        int* __restrict__ row_start,
                                                        float* __restrict__ dinv,
                                                        int* __restrict__ csr_src,
                                                        int n) {
    __shared__ int cnt64[64];
    __shared__ int cur[64];
    int b = blockIdx.x;
    int node0 = b << 6;
    int tid = threadIdx.x;
    if (tid < 64) cnt64[tid] = 0;
    __syncthreads();
    int start = bucket_base[b];
    int end = bucket_base[b + 1];
    int e = start + tid;
    for (; e + 768 < end; e += 1024) {
        uint_t u0 = pairs[e], u1 = pairs[e + 256], u2 = pairs[e + 512], u3 = pairs[e + 768];
        atomicAdd(&cnt64[u0 >> 26], 1);
        atomicAdd(&cnt64[u1 >> 26], 1);
        atomicAdd(&cnt64[u2 >> 26], 1);
        atomicAdd(&cnt64[u3 >> 26], 1);
    }
    for (; e < end; e += 256) atomicAdd(&cnt64[pairs[e] >> 26], 1);
    __syncthreads();
    if (tid < 64) {
        int c = cnt64[tid];
        int v = c;
        #pragma unroll
        for (int off = 1; off < 64; off <<= 1) {
            int u = __shfl_up(v, off, 64);
            if (tid >= off) v += u;
        }
        int excl = start + v - c;
        if (node0 + tid < n) {
            row_start[node0 + tid] = excl;
            dinv[node0 + tid] = rsqrtf((float)(c + 1));  // +1 self loop
        }
        cur[tid] = excl;
    }
    __syncthreads();
    e = start + tid;
    for (; e + 768 < end; e += 1024) {
        uint_t u0 = pairs[e], u1 = pairs[e + 256], u2 = pairs[e + 512], u3 = pairs[e + 768];
        int p0 = atomicAdd(&cur[u0 >> 26], 1);
        int p1 = atomicAdd(&cur[u1 >> 26], 1);
        int p2 = atomicAdd(&cur[u2 >> 26], 1);
        int p3 = atomicAdd(&cur[u3 >> 26], 1);
        csr_src[p0] = (int)(u0 & 0x3FFFFFFu);
        csr_src[p1] = (int)(u1 & 0x3FFFFFFu);
        csr_src[p2] = (int)(u2 & 0x3FFFFFFu);
        csr_src[p3] = (int)(u3 & 0x3FFFFFFu);
    }
    for (; e < end; e += 256) {
        uint_t u = pairs[e];
        int p = atomicAdd(&cur[u >> 26], 1);
        csr_src[p] = (int)(u & 0x3FFFFFFu);
    }
}

// ---------------- W prep: transposed bf16 hi/lo splits ----------------
// w1h/w1l: [128 cols][128 k]; w2h/w2l: [64 cols][128 k]. Wt[c][k] = W[k][c].
__global__ __launch_bounds__(256) void wsplit_kernel(const float* __restrict__ W1,
                                                     const float* __restrict__ W2,
                                                     ushort_t* __restrict__ w1h,
                                                     ushort_t* __restrict__ w1l,
                                                     ushort_t* __restrict__ w2h,
                                                     ushort_t* __restrict__ w2l) {
    int idx = blockIdx.x * 256 + threadIdx.x;
    const int tot1 = 128 * 128;
    const int tot = tot1 + 64 * 128;
    if (idx >= tot) return;
    float v;
    ushort_t* ph;
    ushort_t* pl;
    int o;
    if (idx < tot1) {
        int c = idx >> 7, k = idx & 127;
        v = W1[k * 128 + c];
        ph = w1h; pl = w1l; o = idx;
    } else {
        int j = idx - tot1;
        int c = j >> 7, k = j & 127;
        v = W2[k * 64 + c];
        ph = w2h; pl = w2l; o = j;
    }
    ushort_t h = f32_to_bf16_rn(v);
    float hv = __uint_as_float((uint_t)h << 16);
    ph[o] = h;
    pl[o] = f32_to_bf16_rn(v - hv);
}

// ---------------- MFMA GEMM: Y[n x NCOL] = (X[n x 128] @ W) * rowscale[row] -------
// hi/lo split: F32_IN: 3 terms (xh*wh + xh*wl + xl*wh); bf16 in: 2 terms (exact A).
// Fragment maps (v_mfma_f32_16x16x32_bf16): A row=lane&15, k=(lane>>4)*8+j;
// B col=lane&15, k=(lane>>4)*8+j; D col=lane&15, row=(lane>>4)*4+reg.
template <int NCOL, bool F32_IN>
__global__ __launch_bounds__(256) void mfma_gemm_kernel(const void* __restrict__ Xv,
                                                        const ushort_t* __restrict__ Wth,
                                                        const ushort_t* __restrict__ Wtl,
                                                        const float* __restrict__ rowscale,
                                                        ushort_t* __restrict__ Y, int n) {
    constexpr int NT = NCOL / 16;        // N tiles (8 or 4)
    const float* X = (const float*)Xv;
    const ushort_t* Hb = (const ushort_t*)Xv;

    int tid = threadIdx.x;
    int wave = tid >> 6;
    int lane = tid & 63;
    int q = lane >> 4;                   // quarter: k-window selector
    int r16 = lane & 15;                 // A row / B,D col within tile
    int rowBase = blockIdx.x * 64 + wave * 16;
    int arow = rowBase + r16;
    if (arow > n - 1) arow = n - 1;      // clamp (dup loads; stores guarded)

    f32x4 acc[NT];
    #pragma unroll
    for (int t = 0; t < NT; t++) acc[t] = (f32x4){0.f, 0.f, 0.f, 0.f};

    #pragma unroll
    for (int ks = 0; ks < 4; ks++) {
        int k0 = ks * 32 + q * 8;        // element index in K
        bf16x8 ah, al = {};
        if (F32_IN) {
            const float4* xr = (const float4*)(X + (size_t)arow * 128 + k0);
            float4 p0 = xr[0], p1 = xr[1];
            float v[8] = {p0.x, p0.y, p0.z, p0.w, p1.x, p1.y, p1.z, p1.w};
            #pragma unroll
            for (int j = 0; j < 8; j++) {
                ushort_t hb = f32_to_bf16_rn(v[j]);
                float hv = __uint_as_float((uint_t)hb << 16);
                ah[j] = (short)hb;
                al[j] = (short)f32_to_bf16_rn(v[j] - hv);
            }
        } else {
            ah = *(const bf16x8*)(Hb + (size_t)arow * 128 + k0);
        }
        #pragma unroll
        for (int t = 0; t < NT; t++) {
            size_t wo = (size_t)(t * 16 + r16) * 128 + k0;
            bf16x8 bh = *(const bf16x8*)(Wth + wo);
            bf16x8 bl = *(const bf16x8*)(Wtl + wo);
            acc[t] = __builtin_amdgcn_mfma_f32_16x16x32_bf16(ah, bh, acc[t], 0, 0, 0);
            acc[t] = __builtin_amdgcn_mfma_f32_16x16x32_bf16(ah, bl, acc[t], 0, 0, 0);
            if (F32_IN)
                acc[t] = __builtin_amdgcn_mfma_f32_16x16x32_bf16(al, bh, acc[t], 0, 0, 0);
        }
    }

    #pragma unroll
    for (int rr = 0; rr < 4; rr++) {
        int row = rowBase + q * 4 + rr;
        if (row < n) {
            float rs = rowscale[row];
            #pragma unroll
            for (int t = 0; t < NT; t++)
                Y[(size_t)row * NCOL + t * 16 + r16] = f32_to_bf16_rn(acc[t][rr] * rs);
        }
    }
}

// ---------------- aggregation layer 1: pull + bias + relu + L2 rownorm ----------------
// xw rows are pre-scaled by dinv[src]; result = dinv[i]*(self + sum) + b1.
__global__ __launch_bounds__(256) void agg1_kernel(const ushort_t* __restrict__ xw,
                                                   const int* __restrict__ csr_src,
                                                   const int* __restrict__ row_start,
                                                   const float* __restrict__ dinv,
                                                   const float* __restrict__ b1,
                                                   ushort_t* __restrict__ h, int n) {
    int wid = (blockIdx.x * 256 + threadIdx.x) >> 6;
    int lane = threadIdx.x & 63;
    if (wid >= n) return;
    int i = wid;
    float di = dinv[i];
    int e0 = row_start[i], e1 = row_start[i + 1];
    uint_t su = ((const uint_t*)(xw + (size_t)i * HID))[lane];
    float ax = bf16lo_to_f32(su), ay = bf16hi_to_f32(su);
    int e = e0;
    // full 8-batches: pure adds (dinv[src] pre-folded into xw rows)
    for (; e + 8 <= e1; e += 8) {
        int s[8];
        #pragma unroll
        for (int j = 0; j < 8; j++) s[j] = csr_src[e + j];
        uint_t v[8];
        #pragma unroll
        for (int j = 0; j < 8; j++)
            v[j] = ((const uint_t*)(xw + (size_t)s[j] * HID))[lane];
        #pragma unroll
        for (int j = 0; j < 8; j++) {
            ax += bf16lo_to_f32(v[j]);
            ay += bf16hi_to_f32(v[j]);
        }
    }
    // masked tail batch replaces the old serial remainder loop.
    // Padded slots re-load the last row (L1-hot) with coefficient 0.
    if (e < e1) {
        int last = e1 - 1;
        int s[8];
        #pragma unroll
        for (int j = 0; j < 8; j++) {
            int idx = e + j;
            s[j] = csr_src[idx <= last ? idx : last];
        }
        uint_t v[8];
        #pragma unroll
        for (int j = 0; j < 8; j++)
            v[j] = ((const uint_t*)(xw + (size_t)s[j] * HID))[lane];
        #pragma unroll
        for (int j = 0; j < 8; j++) {
            float c = (e + j <= last) ? 1.0f : 0.0f;
            ax = fmaf(bf16lo_to_f32(v[j]), c, ax);
            ay = fmaf(bf16hi_to_f32(v[j]), c, ay);
        }
    }
    ax = fmaf(ax, di, b1[lane * 2]);
    ay = fmaf(ay, di, b1[lane * 2 + 1]);
    ax = fmaxf(ax, 0.f);
    ay = fmaxf(ay, 0.f);
    float ss = ax * ax + ay * ay;
    #pragma unroll
    for (int m = 32; m >= 1; m >>= 1) ss += __shfl_xor(ss, m, 64);
    float scale = 1.0f / fmaxf(sqrtf(ss), 1e-12f);
    uint_t u = (uint_t)f32_to_bf16_rn(ax * scale) |
               ((uint_t)f32_to_bf16_rn(ay * scale) << 16);
    ((uint_t*)(h + (size_t)i * HID))[lane] = u;
}

// ---------------- aggregation layer 2: pull + bias -> d_out (f32) ----------------
// hw rows pre-scaled by dinv[src]; result = dinv[i]*(self + sum) + b2.
__global__ __launch_bounds__(256) void agg2_kernel(const ushort_t* __restrict__ hw,
                                                   const int* __restrict__ csr_src,
                                                   const int* __restrict__ row_start,
                                                   const float* __restrict__ dinv,
                                                   const float* __restrict__ b2,
                                                   float* __restrict__ out, int n) {
    int wid = (blockIdx.x * 256 + threadIdx.x) >> 6;
    int lane = threadIdx.x & 63;
    int i = wid * 2 + (lane >> 5);
    int l = lane & 31;
    if (i >= n) return;
    float di = dinv[i];
    uint_t su = ((const uint_t*)(hw + (size_t)i * OUT_CH))[l];
    float ax = bf16lo_to_f32(su), ay = bf16hi_to_f32(su);
    int e0 = row_start[i], e1 = row_start[i + 1];
    int e = e0;
    for (; e + 8 <= e1; e += 8) {
        int s[8];
        #pragma unroll
        for (int j = 0; j < 8; j++) s[j] = csr_src[e + j];
        uint_t v[8];
        #pragma unroll
        for (int j = 0; j < 8; j++)
            v[j] = ((const uint_t*)(hw + (size_t)s[j] * OUT_CH))[l];
        #pragma unroll
        for (int j = 0; j < 8; j++) {
            ax += bf16lo_to_f32(v[j]);
            ay += bf16hi_to_f32(v[j]);
        }
    }
    if (e < e1) {
        int last = e1 - 1;
        int s[8];
        #pragma unroll
        for (int j = 0; j < 8; j++) {
            int idx = e + j;
            s[j] = csr_src[idx <= last ? idx : last];
        }
        uint_t v[8];
        #pragma unroll
        for (int j = 0; j < 8; j++)
            v[j] = ((const uint_t*)(hw + (size_t)s[j] * OUT_CH))[l];
        #pragma unroll
        for (int j = 0; j < 8; j++) {
            float c = (e + j <= last) ? 1.0f : 0.0f;
            ax = fmaf(bf16lo_to_f32(v[j]), c, ax);
            ay = fmaf(bf16hi_to_f32(v[j]), c, ay);
        }
    }
    ax = fmaf(ax, di, b2[l * 2]);
    ay = fmaf(ay, di, b2[l * 2 + 1]);
    ((float2*)(out + (size_t)i * OUT_CH))[l] = make_float2(ax, ay);
}

extern "C" void kernel_launch(void* const* d_in, const int* in_sizes, int n_in,
                              void* d_out, int out_size, void* d_ws, size_t ws_size,
                              hipStream_t stream) {
    const float* x  = (const float*)d_in[0];
    const int*   ei = (const int*)d_in[1];
    const float* W1 = (const float*)d_in[2];
    const float* b1 = (const float*)d_in[3];
    const float* W2 = (const float*)d_in[4];
    const float* b2 = (const float*)d_in[5];
    float* out = (float*)d_out;

    const int N = in_sizes[0] / IN_CH;     // 100000
    const int E = in_sizes[1] / 2;         // 1600000
    const int* src = ei;
    const int* dst = ei + E;
    const int NB = (N + 63) / 64;          // buckets (1563)
    const int chunk = (E + NBLK - 1) / NBLK;

    // ---- workspace carve ----
    char* base = (char*)d_ws;
    size_t off = 0;
    auto alloc = [&](size_t bytes) -> void* {
        void* p = base + off;
        off = (off + bytes + 255) & ~(size_t)255;
        return p;
    };
    int*      blk_cnt     = (int*)alloc((size_t)NBLK * NB * 4);
    int*      blk_start   = (int*)alloc((size_t)NBLK * NB * 4);
    int*      btot        = (int*)alloc((size_t)NB * 4);
    int*      bucket_base = (int*)alloc((size_t)(NB + 1) * 4);
    int*      row_start   = (int*)alloc((size_t)(N + 1) * 4);
    float*    dinv        = (float*)alloc((size_t)N * 4);
    int*      csr_src     = (int*)alloc((size_t)E * 4);
    uint_t*   pairs       = (uint_t*)alloc((size_t)E * 4);
    ushort_t* xw          = (ushort_t*)alloc((size_t)N * HID * 2);
    ushort_t* h           = (ushort_t*)alloc((size_t)N * HID * 2);
    ushort_t* hw          = (ushort_t*)alloc((size_t)N * OUT_CH * 2);
    ushort_t* w1h         = (ushort_t*)alloc((size_t)128 * 128 * 2);
    ushort_t* w1l         = (ushort_t*)alloc((size_t)128 * 128 * 2);
    ushort_t* w2h         = (ushort_t*)alloc((size_t)64 * 128 * 2);
    ushort_t* w2l         = (ushort_t*)alloc((size_t)64 * 128 * 2);
    (void)ws_size;

    // W splits (tiny; runs while CSR build occupies the queue)
    wsplit_kernel<<<(128 * 128 + 64 * 128 + 255) / 256, 256, 0, stream>>>(
        W1, W2, w1h, w1l, w2h, w2l);

    // CSR build -- no global atomics anywhere
    hist_kernel<<<NBLK, 256, 0, stream>>>(dst, E, chunk, NB, blk_cnt);
    btot_kernel<<<(NB + 255) / 256, 256, 0, stream>>>(blk_cnt, NB, btot);
    scan_kernel<<<1, 256, 0, stream>>>(btot, NB, bucket_base, row_start, N, E);
    colscan_kernel<<<(NB + 15) / 16, 256, 0, stream>>>(blk_cnt, bucket_base, NB, blk_start);
    scatter_kernel<<<NBLK, 256, 0, stream>>>(src, dst, E, chunk, NB, blk_start, pairs);
    fine_fill_kernel<<<NB, 256, 0, stream>>>(pairs, bucket_base, row_start, dinv,
                                             csr_src, N);

    // layer 1 (MFMA, 3-term hi/lo split; xw pre-scaled by dinv[row])
    mfma_gemm_kernel<128, true><<<(N + 63) / 64, 256, 0, stream>>>(
        x, w1h, w1l, dinv, xw, N);
    agg1_kernel<<<(N * 64 + 255) / 256, 256, 0, stream>>>(xw, csr_src, row_start,
                                                          dinv, b1, h, N);
    // layer 2 (MFMA, 2-term; hw pre-scaled by dinv[row])
    mfma_gemm_kernel<64, false><<<(N + 63) / 64, 256, 0, stream>>>(
        h, w2h, w2l, dinv, hw, N);
    int waves2 = (N + 1) / 2;
    agg2_kernel<<<(waves2 * 64 + 255) / 256, 256, 0, stream>>>(hw, csr_src, row_start,
                                                               dinv, b2, out, N);
}

// Round 5
// 291.712 us; speedup vs baseline: 1.3176x; 1.1889x over previous
//
#include <hip/hip_runtime.h>
#include <hip/hip_bf16.h>

// GCN encoder: 2x GCNConv, symmetric norm, relu + L2 rownorm between.
// Pull aggregation over CSR-by-dst, bf16 intermediates (f32 accumulate).
// R7: CSR built with ZERO global atomics (LDS histograms + scans).
// R8: agg loops fully batched; dinv[src] folded into GEMM epilogue.
// R9: GEMMs on MFMA 16x16x32 bf16, hi/lo split (f32-equiv accuracy). 70us:
//     latency-bound (MfmaUtil 5%, VALUBusy 7%) -- 32 serialized {B-load ->
//     3 MFMA} steps/wave, VGPR=68 => nothing in flight, B set (64KB) > L1.
// R10 (this round): B staged in XOR-swizzled LDS once per block (ds_read
// ~120cy, conflict-free, no L1 thrash); 2 row-tiles/wave (32 rows, 128/block)
// => 2 independent MFMA chains per B-fragment + half the B reads. Math and
// accumulation order UNCHANGED from R9 => absmax must stay 0.001953125.

#define IN_CH 128
#define HID 128
#define OUT_CH 64
#define NBLK 128          // chunk blocks for hist/scatter
#define MAXNB 1568        // >= ceil(100000/64)=1563 buckets

typedef unsigned int uint_t;
typedef unsigned short ushort_t;
typedef __attribute__((ext_vector_type(8))) short bf16x8;
typedef __attribute__((ext_vector_type(4))) float f32x4;

__device__ __forceinline__ ushort_t f32_to_bf16_rn(float f) {
    uint_t u = __float_as_uint(f);
    u = (u + 0x7fffu + ((u >> 16) & 1u)) >> 16;
    return (ushort_t)u;
}
__device__ __forceinline__ float bf16lo_to_f32(uint_t u) { return __uint_as_float(u << 16); }
__device__ __forceinline__ float bf16hi_to_f32(uint_t u) { return __uint_as_float(u & 0xffff0000u); }

// ---------------- phase 1: per-block LDS bucket histogram ----------------
__global__ __launch_bounds__(256) void hist_kernel(const int* __restrict__ dst, int E,
                                                   int chunk, int NB,
                                                   int* __restrict__ blk_cnt) {
    __shared__ int hist[MAXNB];
    int tid = threadIdx.x;
    int blk = blockIdx.x;
    for (int b = tid; b < NB; b += 256) hist[b] = 0;
    __syncthreads();
    int start = blk * chunk;
    int end = start + chunk; if (end > E) end = E;
    int e = start + tid;
    for (; e + 768 < end; e += 1024) {
        int d0 = dst[e], d1 = dst[e + 256], d2 = dst[e + 512], d3 = dst[e + 768];
        atomicAdd(&hist[d0 >> 6], 1);
        atomicAdd(&hist[d1 >> 6], 1);
        atomicAdd(&hist[d2 >> 6], 1);
        atomicAdd(&hist[d3 >> 6], 1);
    }
    for (; e < end; e += 256) atomicAdd(&hist[dst[e] >> 6], 1);
    __syncthreads();
    for (int b = tid; b < NB; b += 256) blk_cnt[blk * NB + b] = hist[b];
}

// ---------------- phase 2a: bucket totals (column sums) ----------------
__global__ __launch_bounds__(256) void btot_kernel(const int* __restrict__ blk_cnt,
                                                   int NB, int* __restrict__ btot) {
    int b = blockIdx.x * 256 + threadIdx.x;
    if (b < NB) {
        int sum = 0;
        #pragma unroll 8
        for (int blk = 0; blk < NBLK; blk++) sum += blk_cnt[blk * NB + b];
        btot[b] = sum;
    }
}

// ---------------- phase 2b: single-block exclusive scan over buckets --------------
__global__ __launch_bounds__(256) void scan_kernel(const int* __restrict__ btot, int NB,
                                                   int* __restrict__ bucket_base,
                                                   int* __restrict__ row_start,
                                                   int n, int E) {
    __shared__ int sdata[256];
    __shared__ int carryS;
    int tid = threadIdx.x;
    if (tid == 0) carryS = 0;
    __syncthreads();
    int nchunks = (NB + 255) / 256;
    for (int c = 0; c < nchunks; c++) {
        int i = c * 256 + tid;
        int v = (i < NB) ? btot[i] : 0;
        sdata[tid] = v;
        __syncthreads();
        for (int off = 1; off < 256; off <<= 1) {
            int t = (tid >= off) ? sdata[tid - off] : 0;
            __syncthreads();
            sdata[tid] += t;
            __syncthreads();
        }
        if (i < NB) bucket_base[i] = carryS + sdata[tid] - v;
        __syncthreads();
        if (tid == 0) carryS += sdata[255];
        __syncthreads();
    }
    if (tid == 0) {
        bucket_base[NB] = E;
        row_start[n] = E;
    }
}

// ---------------- phase 2c: per-bucket exclusive scan over blocks -----------------
__global__ __launch_bounds__(256) void colscan_kernel(const int* __restrict__ blk_cnt,
                                                      const int* __restrict__ bucket_base,
                                                      int NB, int* __restrict__ blk_start) {
    __shared__ int tile[NBLK][16];
    int tid = threadIdx.x;
    int b0 = blockIdx.x * 16;
    for (int idx = tid; idx < NBLK * 16; idx += 256) {
        int blk = idx >> 4, b = idx & 15;
        if (b0 + b < NB) tile[blk][b] = blk_cnt[blk * NB + b0 + b];
    }
    __syncthreads();
    if (tid < 16 && b0 + tid < NB) {
        int running = bucket_base[b0 + tid];
        for (int blk = 0; blk < NBLK; blk++) {
            int t = tile[blk][tid];
            tile[blk][tid] = running;
            running += t;
        }
    }
    __syncthreads();
    for (int idx = tid; idx < NBLK * 16; idx += 256) {
        int blk = idx >> 4, b = idx & 15;
        if (b0 + b < NB) blk_start[blk * NB + b0 + b] = tile[blk][b];
    }
}

// ---------------- phase 3: scatter, LDS tickets only ----------------
// pack: src (26 bits) | (dst & 63) << 26.
__global__ __launch_bounds__(256) void scatter_kernel(const int* __restrict__ src,
                                                      const int* __restrict__ dst,
                                                      int E, int chunk, int NB,
                                                      const int* __restrict__ blk_start,
                                                      uint_t* __restrict__ pairs) {
    __shared__ int cur[MAXNB];
    int tid = threadIdx.x;
    int blk = blockIdx.x;
    for (int b = tid; b < NB; b += 256) cur[b] = blk_start[blk * NB + b];
    __syncthreads();
    int start = blk * chunk;
    int end = start + chunk; if (end > E) end = E;
    int e = start + tid;
    for (; e + 768 < end; e += 1024) {
        int d0 = dst[e], d1 = dst[e + 256], d2 = dst[e + 512], d3 = dst[e + 768];
        int s0 = src[e], s1 = src[e + 256], s2 = src[e + 512], s3 = src[e + 768];
        int p0 = atomicAdd(&cur[d0 >> 6], 1);
        int p1 = atomicAdd(&cur[d1 >> 6], 1);
        int p2 = atomicAdd(&cur[d2 >> 6], 1);
        int p3 = atomicAdd(&cur[d3 >> 6], 1);
        pairs[p0] = (uint_t)s0 | ((uint_t)(d0 & 63) << 26);
        pairs[p1] = (uint_t)s1 | ((uint_t)(d1 & 63) << 26);
        pairs[p2] = (uint_t)s2 | ((uint_t)(d2 & 63) << 26);
        pairs[p3] = (uint_t)s3 | ((uint_t)(d3 & 63) << 26);
    }
    for (; e < end; e += 256) {
        int d = dst[e], s = src[e];
        int p = atomicAdd(&cur[d >> 6], 1);
        pairs[p] = (uint_t)s | ((uint_t)(d & 63) << 26);
    }
}

// ---------------- phase 4: fine fill -- per bucket: counts, row_start, dinv, csr ---
__global__ __launch_bounds__(256) void fine_fill_kernel(const uint_t* __restrict__ pairs,
                                                        const int* __restrict__ bucket_base,
                                                        int* __restrict__ row_start,
                                                        float* __restrict__ dinv,
                                                        int* __restrict__ csr_src,
                                                        int n) {
    __shared__ int cnt64[64];
    __shared__ int cur[64];
    int b = blockIdx.x;
    int node0 = b << 6;
    int tid = threadIdx.x;
    if (tid < 64) cnt64[tid] = 0;
    __syncthreads();
    int start = bucket_base[b];
    int end = bucket_base[b + 1];
    int e = start + tid;
    for (; e + 768 < end; e += 1024) {
        uint_t u0 = pairs[e], u1 = pairs[e + 256], u2 = pairs[e + 512], u3 = pairs[e + 768];
        atomicAdd(&cnt64[u0 >> 26], 1);
        atomicAdd(&cnt64[u1 >> 26], 1);
        atomicAdd(&cnt64[u2 >> 26], 1);
        atomicAdd(&cnt64[u3 >> 26], 1);
    }
    for (; e < end; e += 256) atomicAdd(&cnt64[pairs[e] >> 26], 1);
    __syncthreads();
    if (tid < 64) {
        int c = cnt64[tid];
        int v = c;
        #pragma unroll
        for (int off = 1; off < 64; off <<= 1) {
            int u = __shfl_up(v, off, 64);
            if (tid >= off) v += u;
        }
        int excl = start + v - c;
        if (node0 + tid < n) {
            row_start[node0 + tid] = excl;
            dinv[node0 + tid] = rsqrtf((float)(c + 1));  // +1 self loop
        }
        cur[tid] = excl;
    }
    __syncthreads();
    e = start + tid;
    for (; e + 768 < end; e += 1024) {
        uint_t u0 = pairs[e], u1 = pairs[e + 256], u2 = pairs[e + 512], u3 = pairs[e + 768];
        int p0 = atomicAdd(&cur[u0 >> 26], 1);
        int p1 = atomicAdd(&cur[u1 >> 26], 1);
        int p2 = atomicAdd(&cur[u2 >> 26], 1);
        int p3 = atomicAdd(&cur[u3 >> 26], 1);
        csr_src[p0] = (int)(u0 & 0x3FFFFFFu);
        csr_src[p1] = (int)(u1 & 0x3FFFFFFu);
        csr_src[p2] = (int)(u2 & 0x3FFFFFFu);
        csr_src[p3] = (int)(u3 & 0x3FFFFFFu);
    }
    for (; e < end; e += 256) {
        uint_t u = pairs[e];
        int p = atomicAdd(&cur[u >> 26], 1);
        csr_src[p] = (int)(u & 0x3FFFFFFu);
    }
}

// ---------------- W prep: transposed bf16 hi/lo splits ----------------
// w1h/w1l: [128 cols][128 k]; w2h/w2l: [64 cols][128 k]. Wt[c][k] = W[k][c].
__global__ __launch_bounds__(256) void wsplit_kernel(const float* __restrict__ W1,
                                                     const float* __restrict__ W2,
                                                     ushort_t* __restrict__ w1h,
                                                     ushort_t* __restrict__ w1l,
                                                     ushort_t* __restrict__ w2h,
                                                     ushort_t* __restrict__ w2l) {
    int idx = blockIdx.x * 256 + threadIdx.x;
    const int tot1 = 128 * 128;
    const int tot = tot1 + 64 * 128;
    if (idx >= tot) return;
    float v;
    ushort_t* ph;
    ushort_t* pl;
    int o;
    if (idx < tot1) {
        int c = idx >> 7, k = idx & 127;
        v = W1[k * 128 + c];
        ph = w1h; pl = w1l; o = idx;
    } else {
        int j = idx - tot1;
        int c = j >> 7, k = j & 127;
        v = W2[k * 64 + c];
        ph = w2h; pl = w2l; o = j;
    }
    ushort_t h = f32_to_bf16_rn(v);
    float hv = __uint_as_float((uint_t)h << 16);
    ph[o] = h;
    pl[o] = f32_to_bf16_rn(v - hv);
}

// ---------------- MFMA GEMM: Y[n x NCOL] = (X[n x 128] @ W) * rowscale[row] -------
// hi/lo split: F32_IN: 3 terms (xh*wh + xh*wl + xl*wh); bf16 in: 2 terms (exact A).
// B staged in XOR-swizzled LDS (byte ^= (row&7)<<4): conflict-free ds_read_b128,
// no L1 thrash. 4 waves x 32 rows = 128 rows/block; 2 row-tiles/wave for ILP.
// Fragment maps (v_mfma_f32_16x16x32_bf16): A row=lane&15, k=(lane>>4)*8+j;
// B col=lane&15, k=(lane>>4)*8+j; D col=lane&15, row=(lane>>4)*4+reg.
template <int NCOL, bool F32_IN>
__global__ __launch_bounds__(256, 2) void mfma_gemm_kernel(const void* __restrict__ Xv,
                                                           const ushort_t* __restrict__ Wth,
                                                           const ushort_t* __restrict__ Wtl,
                                                           const float* __restrict__ rowscale,
                                                           ushort_t* __restrict__ Y, int n) {
    constexpr int NT = NCOL / 16;          // col tiles (8 or 4)
    constexpr int WB = NCOL * 128 * 2;     // bytes per W array (h or l)
    constexpr int NCH = WB / 16;           // 16B chunks per array
    __shared__ __align__(16) char Bs[2 * WB];   // h @0, l @WB; swizzled

    int tid = threadIdx.x;

    // ---- stage B, swizzled (reg-staged: global_load_lds can't swizzle) ----
    for (int i = tid; i < 2 * NCH; i += 256) {
        bool lo = (i >= NCH);
        int j = lo ? i - NCH : i;
        int row = j >> 4, c = j & 15;        // row = W col index; 16 chunks/row
        bf16x8 v = *(const bf16x8*)((lo ? Wtl : Wth) + row * 128 + c * 8);
        int bo = (row << 8) + (c << 4);
        bo ^= (row & 7) << 4;                // T2 swizzle
        *(bf16x8*)(Bs + (lo ? WB : 0) + bo) = v;
    }
    __syncthreads();

    int wave = tid >> 6;
    int lane = tid & 63;
    int q = lane >> 4;                       // k-quarter selector
    int r16 = lane & 15;                     // A row / B,D col within tile
    int rowBase = blockIdx.x * 128 + wave * 32;
    int ar0 = rowBase + r16;      if (ar0 > n - 1) ar0 = n - 1;
    int ar1 = rowBase + 16 + r16; if (ar1 > n - 1) ar1 = n - 1;

    const float* X = (const float*)Xv;
    const ushort_t* Hb = (const ushort_t*)Xv;

    f32x4 acc[2][NT];
    #pragma unroll
    for (int rt = 0; rt < 2; rt++)
        #pragma unroll
        for (int t = 0; t < NT; t++) acc[rt][t] = (f32x4){0.f, 0.f, 0.f, 0.f};

    #pragma unroll
    for (int ks = 0; ks < 4; ks++) {
        int k0 = ks * 32 + q * 8;            // element index in K
        bf16x8 ah[2], al[2] = {};
        #pragma unroll
        for (int rt = 0; rt < 2; rt++) {
            int arow = rt ? ar1 : ar0;
            if (F32_IN) {
                const float4* xr = (const float4*)(X + (size_t)arow * 128 + k0);
                float4 p0 = xr[0], p1 = xr[1];
                float v[8] = {p0.x, p0.y, p0.z, p0.w, p1.x, p1.y, p1.z, p1.w};
                #pragma unroll
                for (int j = 0; j < 8; j++) {
                    ushort_t hb = f32_to_bf16_rn(v[j]);
                    float hv = __uint_as_float((uint_t)hb << 16);
                    ah[rt][j] = (short)hb;
                    al[rt][j] = (short)f32_to_bf16_rn(v[j] - hv);
                }
            } else {
                ah[rt] = *(const bf16x8*)(Hb + (size_t)arow * 128 + k0);
            }
        }
        #pragma unroll
        for (int t = 0; t < NT; t++) {
            int bo = ((t * 16 + r16) << 8) + ks * 64 + (q << 4);
            bo ^= (r16 & 7) << 4;            // (t*16+r16)&7 == r16&7
            bf16x8 bh = *(const bf16x8*)(Bs + bo);
            bf16x8 bl = *(const bf16x8*)(Bs + WB + bo);
            #pragma unroll
            for (int rt = 0; rt < 2; rt++) {
                acc[rt][t] = __builtin_amdgcn_mfma_f32_16x16x32_bf16(ah[rt], bh, acc[rt][t], 0, 0, 0);
                acc[rt][t] = __builtin_amdgcn_mfma_f32_16x16x32_bf16(ah[rt], bl, acc[rt][t], 0, 0, 0);
                if (F32_IN)
                    acc[rt][t] = __builtin_amdgcn_mfma_f32_16x16x32_bf16(al[rt], bh, acc[rt][t], 0, 0, 0);
            }
        }
    }

    #pragma unroll
    for (int rt = 0; rt < 2; rt++) {
        #pragma unroll
        for (int rr = 0; rr < 4; rr++) {
            int row = rowBase + rt * 16 + q * 4 + rr;
            if (row < n) {
                float rs = rowscale[row];
                #pragma unroll
                for (int t = 0; t < NT; t++)
                    Y[(size_t)row * NCOL + t * 16 + r16] = f32_to_bf16_rn(acc[rt][t][rr] * rs);
            }
        }
    }
}

// ---------------- aggregation layer 1: pull + bias + relu + L2 rownorm ----------------
// xw rows are pre-scaled by dinv[src]; result = dinv[i]*(self + sum) + b1.
__global__ __launch_bounds__(256) void agg1_kernel(const ushort_t* __restrict__ xw,
                                                   const int* __restrict__ csr_src,
                                                   const int* __restrict__ row_start,
                                                   const float* __restrict__ dinv,
                                                   const float* __restrict__ b1,
                                                   ushort_t* __restrict__ h, int n) {
    int wid = (blockIdx.x * 256 + threadIdx.x) >> 6;
    int lane = threadIdx.x & 63;
    if (wid >= n) return;
    int i = wid;
    float di = dinv[i];
    int e0 = row_start[i], e1 = row_start[i + 1];
    uint_t su = ((const uint_t*)(xw + (size_t)i * HID))[lane];
    float ax = bf16lo_to_f32(su), ay = bf16hi_to_f32(su);
    int e = e0;
    // full 8-batches: pure adds (dinv[src] pre-folded into xw rows)
    for (; e + 8 <= e1; e += 8) {
        int s[8];
        #pragma unroll
        for (int j = 0; j < 8; j++) s[j] = csr_src[e + j];
        uint_t v[8];
        #pragma unroll
        for (int j = 0; j < 8; j++)
            v[j] = ((const uint_t*)(xw + (size_t)s[j] * HID))[lane];
        #pragma unroll
        for (int j = 0; j < 8; j++) {
            ax += bf16lo_to_f32(v[j]);
            ay += bf16hi_to_f32(v[j]);
        }
    }
    // masked tail batch replaces the old serial remainder loop.
    // Padded slots re-load the last row (L1-hot) with coefficient 0.
    if (e < e1) {
        int last = e1 - 1;
        int s[8];
        #pragma unroll
        for (int j = 0; j < 8; j++) {
            int idx = e + j;
            s[j] = csr_src[idx <= last ? idx : last];
        }
        uint_t v[8];
        #pragma unroll
        for (int j = 0; j < 8; j++)
            v[j] = ((const uint_t*)(xw + (size_t)s[j] * HID))[lane];
        #pragma unroll
        for (int j = 0; j < 8; j++) {
            float c = (e + j <= last) ? 1.0f : 0.0f;
            ax = fmaf(bf16lo_to_f32(v[j]), c, ax);
            ay = fmaf(bf16hi_to_f32(v[j]), c, ay);
        }
    }
    ax = fmaf(ax, di, b1[lane * 2]);
    ay = fmaf(ay, di, b1[lane * 2 + 1]);
    ax = fmaxf(ax, 0.f);
    ay = fmaxf(ay, 0.f);
    float ss = ax * ax + ay * ay;
    #pragma unroll
    for (int m = 32; m >= 1; m >>= 1) ss += __shfl_xor(ss, m, 64);
    float scale = 1.0f / fmaxf(sqrtf(ss), 1e-12f);
    uint_t u = (uint_t)f32_to_bf16_rn(ax * scale) |
               ((uint_t)f32_to_bf16_rn(ay * scale) << 16);
    ((uint_t*)(h + (size_t)i * HID))[lane] = u;
}

// ---------------- aggregation layer 2: pull + bias -> d_out (f32) ----------------
// hw rows pre-scaled by dinv[src]; result = dinv[i]*(self + sum) + b2.
__global__ __launch_bounds__(256) void agg2_kernel(const ushort_t* __restrict__ hw,
                                                   const int* __restrict__ csr_src,
                                                   const int* __restrict__ row_start,
                                                   const float* __restrict__ dinv,
                                                   const float* __restrict__ b2,
                                                   float* __restrict__ out, int n) {
    int wid = (blockIdx.x * 256 + threadIdx.x) >> 6;
    int lane = threadIdx.x & 63;
    int i = wid * 2 + (lane >> 5);
    int l = lane & 31;
    if (i >= n) return;
    float di = dinv[i];
    uint_t su = ((const uint_t*)(hw + (size_t)i * OUT_CH))[l];
    float ax = bf16lo_to_f32(su), ay = bf16hi_to_f32(su);
    int e0 = row_start[i], e1 = row_start[i + 1];
    int e = e0;
    for (; e + 8 <= e1; e += 8) {
        int s[8];
        #pragma unroll
        for (int j = 0; j < 8; j++) s[j] = csr_src[e + j];
        uint_t v[8];
        #pragma unroll
        for (int j = 0; j < 8; j++)
            v[j] = ((const uint_t*)(hw + (size_t)s[j] * OUT_CH))[l];
        #pragma unroll
        for (int j = 0; j < 8; j++) {
            ax += bf16lo_to_f32(v[j]);
            ay += bf16hi_to_f32(v[j]);
        }
    }
    if (e < e1) {
        int last = e1 - 1;
        int s[8];
        #pragma unroll
        for (int j = 0; j < 8; j++) {
            int idx = e + j;
            s[j] = csr_src[idx <= last ? idx : last];
        }
        uint_t v[8];
        #pragma unroll
        for (int j = 0; j < 8; j++)
            v[j] = ((const uint_t*)(hw + (size_t)s[j] * OUT_CH))[l];
        #pragma unroll
        for (int j = 0; j < 8; j++) {
            float c = (e + j <= last) ? 1.0f : 0.0f;
            ax = fmaf(bf16lo_to_f32(v[j]), c, ax);
            ay = fmaf(bf16hi_to_f32(v[j]), c, ay);
        }
    }
    ax = fmaf(ax, di, b2[l * 2]);
    ay = fmaf(ay, di, b2[l * 2 + 1]);
    ((float2*)(out + (size_t)i * OUT_CH))[l] = make_float2(ax, ay);
}

extern "C" void kernel_launch(void* const* d_in, const int* in_sizes, int n_in,
                              void* d_out, int out_size, void* d_ws, size_t ws_size,
                              hipStream_t stream) {
    const float* x  = (const float*)d_in[0];
    const int*   ei = (const int*)d_in[1];
    const float* W1 = (const float*)d_in[2];
    const float* b1 = (const float*)d_in[3];
    const float* W2 = (const float*)d_in[4];
    const float* b2 = (const float*)d_in[5];
    float* out = (float*)d_out;

    const int N = in_sizes[0] / IN_CH;     // 100000
    const int E = in_sizes[1] / 2;         // 1600000
    const int* src = ei;
    const int* dst = ei + E;
    const int NB = (N + 63) / 64;          // buckets (1563)
    const int chunk = (E + NBLK - 1) / NBLK;

    // ---- workspace carve ----
    char* base = (char*)d_ws;
    size_t off = 0;
    auto alloc = [&](size_t bytes) -> void* {
        void* p = base + off;
        off = (off + bytes + 255) & ~(size_t)255;
        return p;
    };
    int*      blk_cnt     = (int*)alloc((size_t)NBLK * NB * 4);
    int*      blk_start   = (int*)alloc((size_t)NBLK * NB * 4);
    int*      btot        = (int*)alloc((size_t)NB * 4);
    int*      bucket_base = (int*)alloc((size_t)(NB + 1) * 4);
    int*      row_start   = (int*)alloc((size_t)(N + 1) * 4);
    float*    dinv        = (float*)alloc((size_t)N * 4);
    int*      csr_src     = (int*)alloc((size_t)E * 4);
    uint_t*   pairs       = (uint_t*)alloc((size_t)E * 4);
    ushort_t* xw          = (ushort_t*)alloc((size_t)N * HID * 2);
    ushort_t* h           = (ushort_t*)alloc((size_t)N * HID * 2);
    ushort_t* hw          = (ushort_t*)alloc((size_t)N * OUT_CH * 2);
    ushort_t* w1h         = (ushort_t*)alloc((size_t)128 * 128 * 2);
    ushort_t* w1l         = (ushort_t*)alloc((size_t)128 * 128 * 2);
    ushort_t* w2h         = (ushort_t*)alloc((size_t)64 * 128 * 2);
    ushort_t* w2l         = (ushort_t*)alloc((size_t)64 * 128 * 2);
    (void)ws_size;

    // W splits (tiny)
    wsplit_kernel<<<(128 * 128 + 64 * 128 + 255) / 256, 256, 0, stream>>>(
        W1, W2, w1h, w1l, w2h, w2l);

    // CSR build -- no global atomics anywhere
    hist_kernel<<<NBLK, 256, 0, stream>>>(dst, E, chunk, NB, blk_cnt);
    btot_kernel<<<(NB + 255) / 256, 256, 0, stream>>>(blk_cnt, NB, btot);
    scan_kernel<<<1, 256, 0, stream>>>(btot, NB, bucket_base, row_start, N, E);
    colscan_kernel<<<(NB + 15) / 16, 256, 0, stream>>>(blk_cnt, bucket_base, NB, blk_start);
    scatter_kernel<<<NBLK, 256, 0, stream>>>(src, dst, E, chunk, NB, blk_start, pairs);
    fine_fill_kernel<<<NB, 256, 0, stream>>>(pairs, bucket_base, row_start, dinv,
                                             csr_src, N);

    // layer 1 (MFMA, 3-term hi/lo split; xw pre-scaled by dinv[row])
    mfma_gemm_kernel<128, true><<<(N + 127) / 128, 256, 0, stream>>>(
        x, w1h, w1l, dinv, xw, N);
    agg1_kernel<<<(N * 64 + 255) / 256, 256, 0, stream>>>(xw, csr_src, row_start,
                                                          dinv, b1, h, N);
    // layer 2 (MFMA, 2-term; hw pre-scaled by dinv[row])
    mfma_gemm_kernel<64, false><<<(N + 127) / 128, 256, 0, stream>>>(
        h, w2h, w2l, dinv, hw, N);
    int waves2 = (N + 1) / 2;
    agg2_kernel<<<(waves2 * 64 + 255) / 256, 256, 0, stream>>>(hw, csr_src, row_start,
                                                               dinv, b2, out, N);
}